// Round 6
// baseline (569.607 us; speedup 1.0000x reference)
//
#include <hip/hip_runtime.h>
#include <hip/hip_bf16.h>

#define Bz 16
#define Tz 256
#define T2z 16
#define Hz 256
#define DRz 64
#define DEPTHz 8
#define ROWSz (Bz * (Tz + 2))   // 4128 rows in flat h/c tables
#define NODESz (Bz * Tz)        // 4096 tree nodes

typedef short bf16x8 __attribute__((ext_vector_type(8)));
typedef float f32x4 __attribute__((ext_vector_type(4)));

__device__ __forceinline__ float sigmoid_(float x) { return 1.0f / (1.0f + __expf(-x)); }
__device__ __forceinline__ float tanh_(float x) {
    float e = __expf(2.0f * x);
    return 1.0f - 2.0f / (e + 1.0f);
}
__device__ __forceinline__ short f2b(float f) {
    __hip_bfloat16 h = __float2bfloat16(f);
    return *(short*)&h;
}
__device__ __forceinline__ float b2f(short s) {
    return __uint_as_float(((unsigned)(unsigned short)s) << 16);
}
__device__ __forceinline__ void gload16(const short* g, short* l) {
    __builtin_amdgcn_global_load_lds((const __attribute__((address_space(1))) void*)g,
                                     (__attribute__((address_space(3))) void*)l, 16, 0, 0);
}

// C[M,N] = A[M,K]_bf16 @ BT[N,K]^T (+bias). Output fp32 (C) or bf16 (Cb).
__global__ __launch_bounds__(256) void bgemm_k(const short* __restrict__ A,
                                               const short* __restrict__ BT,
                                               const float* __restrict__ bias,
                                               float* __restrict__ C,
                                               short* __restrict__ Cb,
                                               int K, int N) {
    __shared__ short As[64 * 32];
    __shared__ short Bs[64 * 32];
    const int tid = threadIdx.x;
    const int w = tid >> 6, lane = tid & 63;
    const int m0 = blockIdx.y * 64, n0 = blockIdx.x * 64;
    const int r16 = lane & 15, q = lane >> 4;
    f32x4 acc[4] = {};
    const short* ga = A + (size_t)(m0 + w * 16 + (lane >> 2)) * K + (lane & 3) * 8;
    const short* gb = BT + (size_t)(n0 + w * 16 + (lane >> 2)) * K + (lane & 3) * 8;
    short* la = As + w * 512;
    short* lb = Bs + w * 512;
    for (int kt = 0; kt < K; kt += 32) {
        __syncthreads();
        gload16(ga + kt, la);
        gload16(gb + kt, lb);
        __syncthreads();
        bf16x8 bfrag = *(const bf16x8*)&Bs[(w * 16 + r16) * 32 + q * 8];
#pragma unroll
        for (int i = 0; i < 4; i++) {
            bf16x8 afrag = *(const bf16x8*)&As[(i * 16 + r16) * 32 + q * 8];
            acc[i] = __builtin_amdgcn_mfma_f32_16x16x32_bf16(afrag, bfrag, acc[i], 0, 0, 0);
        }
    }
    const int col = n0 + w * 16 + r16;
    const float bv = bias ? bias[col] : 0.0f;
#pragma unroll
    for (int i = 0; i < 4; i++)
#pragma unroll
        for (int r = 0; r < 4; r++) {
            const size_t o = (size_t)(m0 + i * 16 + q * 4 + r) * N + col;
            if (Cb) Cb[o] = f2b(acc[i][r] + bv);
            else    C[o]  = acc[i][r] + bv;
        }
}

// One-time weight prep: bf16 transposes + composed proj bias [0 | b_hf].
__global__ __launch_bounds__(256) void prep_w_k(const float* __restrict__ Wx,
                                                const float* __restrict__ Whp,
                                                const float* __restrict__ Whf,
                                                const float* __restrict__ bhf,
                                                const float* __restrict__ Whiou,
                                                const float* __restrict__ Wdep,
                                                short* __restrict__ WTx,
                                                short* __restrict__ WTcat,
                                                short* __restrict__ WThiou,
                                                short* __restrict__ WTdep,
                                                float* __restrict__ bias_cat) {
    int e = blockIdx.x * 256 + threadIdx.x;
    if (e < 262144) { int n = e >> 8, k = e & 255; WTx[e] = f2b(Wx[k * 1024 + n]); return; }
    e -= 262144;
    if (e < 131072) {
        int n = e >> 8, k = e & 255;
        WTcat[e] = f2b((n < 256) ? Whp[k * 256 + n] : Whf[k * 256 + (n - 256)]);
        return;
    }
    e -= 131072;
    if (e < 196608) { int n = e >> 8, k = e & 255; WThiou[e] = f2b(Whiou[k * 768 + n]); return; }
    e -= 196608;
    if (e < 16384) { int n = e >> 6, k = e & 63; WTdep[e] = f2b(Wdep[k * 256 + n]); return; }
    e -= 16384;
    if (e < 512) bias_cat[e] = (e < 256) ? 0.0f : bhf[e - 256];
}

__global__ __launch_bounds__(256) void cast_k(const float* __restrict__ s,
                                              short* __restrict__ d, int n4) {
    int i = blockIdx.x * 256 + threadIdx.x;
    if (i < n4) {
        float4 v = ((const float4*)s)[i];
        short4 o; o.x = f2b(v.x); o.y = f2b(v.y); o.z = f2b(v.z); o.w = f2b(v.w);
        ((short4*)d)[i] = o;
    }
}

// xfb[b*16+j][e] = bf16(x_iouf[(b*256+j)*1024 + 768 + e]); 256 rows.
__global__ __launch_bounds__(256) void cast_xf_k(const float* __restrict__ xiouf,
                                                 short* __restrict__ xfb) {
    const int r = blockIdx.x, tid = threadIdx.x;   // r = b*16+j
    const int b = r >> 4, j = r & 15;
    xfb[r * 256 + tid] = f2b(xiouf[(size_t)(b * 256 + j) * 1024 + 768 + tid]);
}

// Level-0 tables: phtab=0; agtab = [pf=b_hf | rh=0 | cb=0].
__global__ __launch_bounds__(256) void init_k(const float* __restrict__ bhf,
                                              short* __restrict__ phtab,
                                              short* __restrict__ agtab) {
    const int r = blockIdx.x, tid = threadIdx.x;
    phtab[(size_t)r * 256 + tid] = 0;
    short* row = agtab + (size_t)r * 768;
    row[tid] = f2b(bhf[tid]);
    row[256 + tid] = 0;
    row[512 + tid] = 0;
}

// Gather stage: one block per node (4096 blocks). TWO-PHASE: all-independent
// logits (phase 1, gathers phtab 2.1 MB) then softmax + all-independent
// aggregation (phase 2, gathers agtab [pf|rh|cb] 6.2 MB). No online chain.
__global__ __launch_bounds__(256) void attn_k(const int* __restrict__ trees,
                                              const float* __restrict__ cmask,
                                              const short* __restrict__ phtab,
                                              const short* __restrict__ agtab,
                                              const short* __restrict__ dp_b,
                                              const float* __restrict__ attnv,
                                              const short* __restrict__ xfb,
                                              short* __restrict__ hjb,
                                              float* __restrict__ fsum) {
    __shared__ int sidx[16];
    __shared__ float smask[16];
    __shared__ float slog[16];
    __shared__ short xfL[16 * 256];   // 8 KB
    __shared__ float hjp[4 * 256];    // 4 KB
    __shared__ float fsp[4 * 256];    // 4 KB
    const int node = blockIdx.x, tid = threadIdx.x;
    const int w = tid >> 6, lane = tid & 63;
    const int e0 = lane * 4;
    const int b = node >> 8;
    if (tid < 16) {
        sidx[tid] = trees[node * 16 + tid];
        smask[tid] = cmask[node * 16 + tid];
        slog[tid] = -1e30f;   // masked children keep -1e30 (weight exactly 0)
    }
    for (int i = tid; i < 512; i += 256)
        ((int4*)xfL)[i] = ((const int4*)(xfb + (size_t)b * 4096))[i];
    __syncthreads();

    const float4 av = *(const float4*)(attnv + e0);
    // ---- Phase 1: logits; wave w children 4w..4w+3, fully independent ----
    {
        short4 ph[4], dv[4];
        bool act[4];
#pragma unroll
        for (int jj = 0; jj < 4; jj++) {   // prefetch all 8 loads first
            const int j = w * 4 + jj;
            act[jj] = (smask[j] != 0.0f);
            if (act[jj]) {
                ph[jj] = *(const short4*)(phtab + (size_t)sidx[j] * 256 + e0);
                dv[jj] = *(const short4*)(dp_b + ((size_t)node * 16 + j) * 256 + e0);
            }
        }
#pragma unroll
        for (int jj = 0; jj < 4; jj++) {
            if (!act[jj]) continue;
            float s = tanh_(b2f(ph[jj].x) + b2f(dv[jj].x)) * av.x
                    + tanh_(b2f(ph[jj].y) + b2f(dv[jj].y)) * av.y
                    + tanh_(b2f(ph[jj].z) + b2f(dv[jj].z)) * av.z
                    + tanh_(b2f(ph[jj].w) + b2f(dv[jj].w)) * av.w;
#pragma unroll
            for (int off = 32; off > 0; off >>= 1) s += __shfl_xor(s, off);
            if (lane == 0) slog[w * 4 + jj] = s;
        }
    }
    __syncthreads();

    // ---- Phase 2: softmax weights (thread-redundant, exact max) + aggregate ----
    float mx = -1e30f;
#pragma unroll
    for (int j = 0; j < 16; j++) mx = fmaxf(mx, slog[j]);
    float den = 0.0f;
#pragma unroll
    for (int j = 0; j < 16; j++) den += __expf(slog[j] - mx);
    const float inv = 1.0f / den;   // all-masked: weights never used (all j skipped)

    float hj0 = 0.f, hj1 = 0.f, hj2 = 0.f, hj3 = 0.f;
    float fs0 = 0.f, fs1 = 0.f, fs2 = 0.f, fs3 = 0.f;
#pragma unroll
    for (int jj = 0; jj < 4; jj++) {
        const int j = w * 4 + jj;
        if (smask[j] == 0.0f) continue;  // exact: ref multiplies masked terms by 0
        const int idx = sidx[j];
        const float wt = __expf(slog[j] - mx) * inv;
        const short* row = agtab + (size_t)idx * 768;
        short4 pf = *(const short4*)(row + e0);
        short4 rh = *(const short4*)(row + 256 + e0);
        short4 cb = *(const short4*)(row + 512 + e0);
        short4 xf = *(const short4*)(xfL + j * 256 + e0);
        hj0 = fmaf(b2f(rh.x), wt, hj0);
        hj1 = fmaf(b2f(rh.y), wt, hj1);
        hj2 = fmaf(b2f(rh.z), wt, hj2);
        hj3 = fmaf(b2f(rh.w), wt, hj3);
        fs0 = fmaf(sigmoid_(b2f(xf.x) + b2f(pf.x)), b2f(cb.x), fs0);
        fs1 = fmaf(sigmoid_(b2f(xf.y) + b2f(pf.y)), b2f(cb.y), fs1);
        fs2 = fmaf(sigmoid_(b2f(xf.z) + b2f(pf.z)), b2f(cb.z), fs2);
        fs3 = fmaf(sigmoid_(b2f(xf.w) + b2f(pf.w)), b2f(cb.w), fs3);
    }
    *(float4*)(hjp + w * 256 + e0) = make_float4(hj0, hj1, hj2, hj3);
    *(float4*)(fsp + w * 256 + e0) = make_float4(fs0, fs1, fs2, fs3);
    __syncthreads();
    // cross-wave combine (plain sums — weights already normalized)
    const float hv = hjp[tid] + hjp[256 + tid] + hjp[512 + tid] + hjp[768 + tid];
    const float fv = fsp[tid] + fsp[256 + tid] + fsp[512 + tid] + fsp[768 + tid];
    hjb[(size_t)node * 256 + tid] = f2b(hv);
    fsum[(size_t)node * 256 + tid] = fv;
}

// Post stage: 16 nodes/block (256 blocks). h_iou MFMA -> gates -> renorm ->
// proj MFMA; writes the split phtab/agtab rows for the next level.
__global__ __launch_bounds__(256, 2) void post_k(const short* __restrict__ hjb,
                                                 const float* __restrict__ fsum,
                                                 const float* __restrict__ xiouf,
                                                 const short* __restrict__ WThiou,
                                                 const float* __restrict__ b_hiou,
                                                 const short* __restrict__ WTcat,
                                                 const float* __restrict__ biascat,
                                                 short* __restrict__ phtab,
                                                 short* __restrict__ agtab,
                                                 float* __restrict__ out,
                                                 int last) {
    __shared__ short hjA[16 * 264];
    __shared__ short htA[16 * 264];
    __shared__ float hiouL[16 * 768];   // 48 KB
    const int tid = threadIdx.x;
    const int w = tid >> 6, lane = tid & 63;
    const int r16 = lane & 15, q = lane >> 4;
    const int node0 = blockIdx.x * 16;
    const int b = node0 >> 8, t0 = node0 & 255;

    // Phase 1: stage hj tile (16 rows x 256 bf16)
    {
        const int row = tid >> 4, c0 = (tid & 15) * 16;
        *(int4*)(hjA + row * 264 + c0) = *(const int4*)(hjb + (size_t)(node0 + row) * 256 + c0);
        *(int4*)(hjA + row * 264 + c0 + 8) = *(const int4*)(hjb + (size_t)(node0 + row) * 256 + c0 + 8);
    }
    __syncthreads();

    // Phase 2: h_iou = hj(16x256) @ W_hiou -> hiouL (bias added in gates)
    for (int f = 0; f < 12; f++) {
        const int nf = w * 12 + f;
        f32x4 acc = {};
#pragma unroll
        for (int kt = 0; kt < 8; kt++) {
            bf16x8 af = *(const bf16x8*)(hjA + r16 * 264 + kt * 32 + q * 8);
            bf16x8 bf = *(const bf16x8*)(WThiou + (size_t)(nf * 16 + r16) * 256 + kt * 32 + q * 8);
            acc = __builtin_amdgcn_mfma_f32_16x16x32_bf16(af, bf, acc, 0, 0, 0);
        }
#pragma unroll
        for (int r = 0; r < 4; r++)
            hiouL[(q * 4 + r) * 768 + nf * 16 + r16] = acc[r];
    }
    __syncthreads();

    // Phase 3: gates + renorm. Thread t: node nl = t>>4, cols e0..e0+15.
    {
        const int nl = tid >> 4, e0 = (tid & 15) * 16;
        const int gnode = node0 + nl;
        const float* xr = xiouf + (size_t)gnode * 1024;
        const float* hl = hiouL + nl * 768;
        float hn[16], cn[16], hs = 0.0f, cs = 0.0f;
#pragma unroll
        for (int u = 0; u < 16; u += 4) {
            float4 xi = *(const float4*)(xr + e0 + u);
            float4 xo = *(const float4*)(xr + 256 + e0 + u);
            float4 xu = *(const float4*)(xr + 512 + e0 + u);
            float4 hi = *(const float4*)(hl + e0 + u);
            float4 ho = *(const float4*)(hl + 256 + e0 + u);
            float4 hu = *(const float4*)(hl + 512 + e0 + u);
            float4 bi = *(const float4*)(b_hiou + e0 + u);
            float4 bo = *(const float4*)(b_hiou + 256 + e0 + u);
            float4 bu = *(const float4*)(b_hiou + 512 + e0 + u);
            float4 fv = *(const float4*)(fsum + (size_t)gnode * 256 + e0 + u);
            float iv[4] = { xi.x + hi.x + bi.x, xi.y + hi.y + bi.y, xi.z + hi.z + bi.z, xi.w + hi.w + bi.w };
            float ov[4] = { xo.x + ho.x + bo.x, xo.y + ho.y + bo.y, xo.z + ho.z + bo.z, xo.w + ho.w + bo.w };
            float uv[4] = { xu.x + hu.x + bu.x, xu.y + hu.y + bu.y, xu.z + hu.z + bu.z, xu.w + hu.w + bu.w };
            float fa[4] = { fv.x, fv.y, fv.z, fv.w };
#pragma unroll
            for (int z = 0; z < 4; z++) {
                const float c = fmaf(sigmoid_(iv[z]), tanh_(uv[z]), fa[z]);
                const float h = sigmoid_(ov[z]) * tanh_(c);
                cn[u + z] = c; hn[u + z] = h;
                hs = fmaf(h, h, hs); cs = fmaf(c, c, cs);
            }
        }
        if (last) {
#pragma unroll
            for (int u = 0; u < 16; u += 4)
                *(float4*)(out + (size_t)gnode * 256 + e0 + u) =
                    make_float4(hn[u], hn[u + 1], hn[u + 2], hn[u + 3]);
            return;  // uniform across grid
        }
#pragma unroll
        for (int off = 8; off > 0; off >>= 1) {
            hs += __shfl_xor(hs, off);
            cs += __shfl_xor(cs, off);
        }
        const float nh = sqrtf(hs), ncv = sqrtf(cs);
        const float sh = nh > 2.0f ? 2.0f / nh : 1.0f;
        const float sc = ncv > 2.0f ? 2.0f / ncv : 1.0f;
        const size_t grow = (size_t)b * (Tz + 2) + t0 + nl + 2;
        short hb[16], cb[16];
#pragma unroll
        for (int u = 0; u < 16; u++) {
            hb[u] = f2b(hn[u] * sh);
            cb[u] = f2b(cn[u] * sc);
        }
#pragma unroll
        for (int u = 0; u < 16; u += 4) {
            *(short4*)(agtab + grow * 768 + 256 + e0 + u) = *(short4*)&hb[u];
            *(short4*)(agtab + grow * 768 + 512 + e0 + u) = *(short4*)&cb[u];
            *(short4*)(htA + nl * 264 + e0 + u) = *(short4*)&hb[u];
        }
    }
    __syncthreads();

    // Phase 4: [ph|pf] = rn_h(16x256) @ [W_hproj|W_hf] + [0|b_hf]
    //          ph -> phtab, pf -> agtab[0..255]
    for (int f = 0; f < 8; f++) {
        const int nf = w * 8 + f;
        f32x4 acc = {};
#pragma unroll
        for (int kt = 0; kt < 8; kt++) {
            bf16x8 af = *(const bf16x8*)(htA + r16 * 264 + kt * 32 + q * 8);
            bf16x8 bf = *(const bf16x8*)(WTcat + (size_t)(nf * 16 + r16) * 256 + kt * 32 + q * 8);
            acc = __builtin_amdgcn_mfma_f32_16x16x32_bf16(af, bf, acc, 0, 0, 0);
        }
        const int col = nf * 16 + r16;
        const float bc = biascat[col];
#pragma unroll
        for (int r = 0; r < 4; r++) {
            const size_t grow = (size_t)b * (Tz + 2) + t0 + q * 4 + r + 2;
            const short v = f2b(acc[r] + bc);
            if (col < 256) phtab[grow * 256 + col] = v;
            else           agtab[grow * 768 + (col - 256)] = v;
        }
    }
}

extern "C" void kernel_launch(void* const* d_in, const int* in_sizes, int n_in,
                              void* d_out, int out_size, void* d_ws, size_t ws_size,
                              hipStream_t stream) {
    const float* tok     = (const float*)d_in[0];
    const int*   trees   = (const int*)d_in[1];
    const float* cmask   = (const float*)d_in[2];
    const float* cdep    = (const float*)d_in[4];
    const float* W_xiouf = (const float*)d_in[5];
    const float* b_xiouf = (const float*)d_in[6];
    const float* W_hiou  = (const float*)d_in[7];
    const float* b_hiou  = (const float*)d_in[8];
    const float* W_hf    = (const float*)d_in[9];
    const float* b_hf    = (const float*)d_in[10];
    const float* W_dep   = (const float*)d_in[11];
    const float* W_hp    = (const float*)d_in[12];
    const float* W_attnv = (const float*)d_in[13];
    float* out = (float*)d_out;

    char* p = (char*)d_ws;
    auto alloc = [&](size_t bytes) { char* q = p; p += (bytes + 255) & ~255ull; return q; };
    short* phtab  = (short*)alloc((size_t)ROWSz * 256 * 2);        // 2.1 MB
    short* agtab  = (short*)alloc((size_t)ROWSz * 768 * 2);        // 6.3 MB
    short* dp_b   = (short*)alloc((size_t)NODESz * 16 * 256 * 2);  // 33.5 MB
    float* x_iouf = (float*)alloc((size_t)NODESz * 1024 * 4);      // 16.8 MB
    short* xfb    = (short*)alloc((size_t)Bz * 16 * 256 * 2);      // 128 KB
    short* hjb    = (short*)alloc((size_t)NODESz * 256 * 2);
    float* fsumb  = (float*)alloc((size_t)NODESz * 256 * 4);
    short* tok_b  = (short*)alloc((size_t)NODESz * 256 * 2);
    short* cdep_b = (short*)alloc((size_t)NODESz * 16 * 64 * 2);
    short* WTx    = (short*)alloc(262144 * 2);
    short* WTcat  = (short*)alloc(131072 * 2);
    short* WThiou = (short*)alloc(196608 * 2);
    short* WTdep  = (short*)alloc(16384 * 2);
    float* biascat= (float*)alloc(512 * 4);

    prep_w_k<<<2370, 256, 0, stream>>>(W_xiouf, W_hp, W_hf, b_hf, W_hiou, W_dep,
                                       WTx, WTcat, WThiou, WTdep, biascat);
    cast_k<<<1024, 256, 0, stream>>>(tok, tok_b, 262144);
    cast_k<<<4096, 256, 0, stream>>>(cdep, cdep_b, 1048576);
    init_k<<<ROWSz, 256, 0, stream>>>(b_hf, phtab, agtab);

    bgemm_k<<<dim3(16, 64), 256, 0, stream>>>(tok_b, WTx, b_xiouf, x_iouf, nullptr, 256, 1024);
    cast_xf_k<<<256, 256, 0, stream>>>(x_iouf, xfb);
    bgemm_k<<<dim3(4, 1024), 256, 0, stream>>>(cdep_b, WTdep, nullptr, nullptr, dp_b, 64, 256);

    for (int lvl = 0; lvl < DEPTHz; lvl++) {
        attn_k<<<NODESz, 256, 0, stream>>>(trees, cmask, phtab, agtab, dp_b,
                                           W_attnv, xfb, hjb, fsumb);
        post_k<<<NODESz / 16, 256, 0, stream>>>(hjb, fsumb, x_iouf,
                                                WThiou, b_hiou, WTcat, biascat,
                                                phtab, agtab, out, lvl == DEPTHz - 1);
    }
}